// Round 8
// baseline (610.518 us; speedup 1.0000x reference)
//
#include <hip/hip_runtime.h>

// Problem constants
constexpr int NN   = 50000;
constexpr int EE   = 800000;
constexpr int INF  = 128;   // input feat
constexpr int NH   = 4;     // heads

// ---------- Tiled fp32 GEMM (64x64, 4x4): used for the small PQ GEMM ----------
__global__ __launch_bounds__(256) void gemm_tiled(const float* __restrict__ A,
                                                  const float* __restrict__ B,
                                                  float* __restrict__ C,
                                                  int N, int K, int M) {
    __shared__ float As[16][68];   // [k][row], padded
    __shared__ float Bs[16][64];   // [k][col]
    const int tid = threadIdx.x;
    const int tx = tid & 15, ty = tid >> 4;
    const int row0 = blockIdx.x * 64, col0 = blockIdx.y * 64;

    float acc[4][4] = {};

    for (int k0 = 0; k0 < K; k0 += 16) {
        {
            const int a_row = tid >> 2;
            const int a_k   = (tid & 3) * 4;
            const int gr    = row0 + a_row;
            float4 v = make_float4(0.f, 0.f, 0.f, 0.f);
            if (gr < N) v = *(const float4*)(A + (size_t)gr * K + k0 + a_k);
            As[a_k + 0][a_row] = v.x;
            As[a_k + 1][a_row] = v.y;
            As[a_k + 2][a_row] = v.z;
            As[a_k + 3][a_row] = v.w;
        }
        {
            const int b_k = tid >> 4;
            const int b_c = (tid & 15) * 4;
            float4 w = *(const float4*)(B + (size_t)(k0 + b_k) * M + col0 + b_c);
            *(float4*)&Bs[b_k][b_c] = w;
        }
        __syncthreads();
        #pragma unroll
        for (int kk = 0; kk < 16; ++kk) {
            float4 a = *(const float4*)&As[kk][ty * 4];
            float4 b = *(const float4*)&Bs[kk][tx * 4];
            const float av[4] = {a.x, a.y, a.z, a.w};
            const float bv[4] = {b.x, b.y, b.z, b.w};
            #pragma unroll
            for (int i = 0; i < 4; ++i)
                #pragma unroll
                for (int j = 0; j < 4; ++j)
                    acc[i][j] = fmaf(av[i], bv[j], acc[i][j]);
        }
        __syncthreads();
    }
    #pragma unroll
    for (int i = 0; i < 4; ++i) {
        const int r = row0 + ty * 4 + i;
        if (r < N) {
            float* cp = C + (size_t)r * M + col0 + tx * 4;
            cp[0] = acc[i][0]; cp[1] = acc[i][1]; cp[2] = acc[i][2]; cp[3] = acc[i][3];
        }
    }
}

// ---------- 128x128-tile fp32 GEMM (8x8 regs) with fused attention epilogue ----------
// 2 FLOP per LDS byte: balanced against the 128 B/cyc LDS pipe (vs 1 FLOP/B at 4x4).
// Col-tile 128 spans whole heads (CH | 128). Reduce a_s/a_d across CH/8 lanes.
template <int CH>
__global__ __launch_bounds__(256) void gemm_att128(const float* __restrict__ A,
                                                   const float* __restrict__ B,
                                                   float* __restrict__ C,
                                                   const float* __restrict__ att_s,
                                                   const float* __restrict__ att_d,
                                                   float* __restrict__ a_s,
                                                   float* __restrict__ a_d,
                                                   int N, int K, int M) {
    __shared__ float As[16][136];  // [k][row], padded (8.7 KB)
    __shared__ float Bs[16][128];  // [k][col]      (8.0 KB)
    const int tid = threadIdx.x;
    const int tx = tid & 15, ty = tid >> 4;
    const int row0 = blockIdx.x * 128, col0 = blockIdx.y * 128;

    // att fragment for this thread's 8 columns (all within one head since 8|CH)
    const int col  = col0 + tx * 8;
    const int head = col / CH;
    const int pos  = col % CH;
    float attS[8], attD[8];
    #pragma unroll
    for (int j = 0; j < 8; ++j) {
        attS[j] = att_s[head * CH + pos + j];
        attD[j] = att_d[head * CH + pos + j];
    }

    float acc[8][8] = {};

    for (int k0 = 0; k0 < K; k0 += 16) {
        // stage A: 128 rows x 16 k = 512 float4; 2 per thread
        #pragma unroll
        for (int q = 0; q < 2; ++q) {
            const int f4 = tid * 2 + q;
            const int row = f4 >> 2;
            const int kq  = f4 & 3;
            const int gr  = row0 + row;
            float4 v = make_float4(0.f, 0.f, 0.f, 0.f);
            if (gr < N) v = *(const float4*)(A + (size_t)gr * K + k0 + kq * 4);
            As[kq * 4 + 0][row] = v.x;
            As[kq * 4 + 1][row] = v.y;
            As[kq * 4 + 2][row] = v.z;
            As[kq * 4 + 3][row] = v.w;
        }
        // stage B: 16 k x 128 cols = 512 float4; 2 per thread
        #pragma unroll
        for (int q = 0; q < 2; ++q) {
            const int f4 = tid * 2 + q;
            const int bk  = f4 >> 5;
            const int bc4 = f4 & 31;
            *(float4*)&Bs[bk][bc4 * 4] =
                *(const float4*)(B + (size_t)(k0 + bk) * M + col0 + bc4 * 4);
        }
        __syncthreads();
        #pragma unroll
        for (int kk = 0; kk < 16; ++kk) {
            const float4 a0 = *(const float4*)&As[kk][ty * 8];
            const float4 a1 = *(const float4*)&As[kk][ty * 8 + 4];
            const float4 b0 = *(const float4*)&Bs[kk][tx * 8];
            const float4 b1 = *(const float4*)&Bs[kk][tx * 8 + 4];
            const float av[8] = {a0.x, a0.y, a0.z, a0.w, a1.x, a1.y, a1.z, a1.w};
            const float bv[8] = {b0.x, b0.y, b0.z, b0.w, b1.x, b1.y, b1.z, b1.w};
            #pragma unroll
            for (int i = 0; i < 8; ++i)
                #pragma unroll
                for (int j = 0; j < 8; ++j)
                    acc[i][j] = fmaf(av[i], bv[j], acc[i][j]);
        }
        __syncthreads();
    }

    #pragma unroll
    for (int i = 0; i < 8; ++i) {
        const int r = row0 + ty * 8 + i;
        if (r < N) {
            float* cp = C + (size_t)r * M + col0 + tx * 8;
            *(float4*)cp       = make_float4(acc[i][0], acc[i][1], acc[i][2], acc[i][3]);
            *(float4*)(cp + 4) = make_float4(acc[i][4], acc[i][5], acc[i][6], acc[i][7]);
        }
        // fused att epilogue
        float ss = 0.f, sd = 0.f;
        #pragma unroll
        for (int j = 0; j < 8; ++j) {
            ss = fmaf(acc[i][j], attS[j], ss);
            sd = fmaf(acc[i][j], attD[j], sd);
        }
        #pragma unroll
        for (int msk = 1; msk < CH / 8; msk <<= 1) {
            ss += __shfl_xor(ss, msk, 64);
            sd += __shfl_xor(sd, msk, 64);
        }
        if ((tx & (CH / 8 - 1)) == 0 && r < N) {
            a_s[r * NH + head] = ss;
            a_d[r * NH + head] = sd;
        }
    }
}

// ---------- CSR build ----------
__global__ __launch_bounds__(256) void count_deg_k(const int* __restrict__ ei,
                                                   int* __restrict__ deg) {
    const int e = blockIdx.x * 256 + threadIdx.x;
    if (e < EE) atomicAdd(&deg[ei[EE + e]], 1);
}

// single-block exclusive scan over deg[0..NN) -> rowptr[0..NN], cursor copy
__global__ __launch_bounds__(1024) void scan_k(const int* __restrict__ deg,
                                               int* __restrict__ rowptr,
                                               int* __restrict__ cursor) {
    __shared__ int wsum[16];
    const int tid = threadIdx.x;
    const int lane = tid & 63, wv = tid >> 6;
    int total = 0;
    for (int base = 0; base < NN; base += 1024) {
        const int i = base + tid;
        const int v = (i < NN) ? deg[i] : 0;
        int incl = v;
        #pragma unroll
        for (int d = 1; d < 64; d <<= 1) {
            int t = __shfl_up(incl, d, 64);
            if (lane >= d) incl += t;
        }
        if (lane == 63) wsum[wv] = incl;
        __syncthreads();
        if (wv == 0) {
            int s = (lane < 16) ? wsum[lane] : 0;
            #pragma unroll
            for (int d = 1; d < 16; d <<= 1) {
                int t = __shfl_up(s, d, 64);
                if (lane >= d) s += t;
            }
            if (lane < 16) wsum[lane] = s;
        }
        __syncthreads();
        const int excl = total + (wv > 0 ? wsum[wv - 1] : 0) + incl - v;
        const int chunk = wsum[15];
        if (i < NN) { rowptr[i] = excl; cursor[i] = excl; }
        total += chunk;
        __syncthreads();   // protect wsum before next iteration's writes
    }
    if (tid == 0) rowptr[NN] = total;
}

__global__ __launch_bounds__(256) void scatter_perm_k(const int* __restrict__ ei,
                                                      int* __restrict__ cursor,
                                                      int* __restrict__ perm,
                                                      int* __restrict__ psrc,
                                                      int* __restrict__ pdst) {
    const int e = blockIdx.x * 256 + threadIdx.x;
    if (e >= EE) return;
    const int d = ei[EE + e];
    const int p = atomicAdd(&cursor[d], 1);
    perm[p] = e;
    psrc[p] = ei[e];
    pdst[p] = d;
}

// ---------- fused per-node edge softmax (CSR, one wave per dst node) ----------
__global__ __launch_bounds__(256) void softmax_csr(const int* __restrict__ rowptr,
                                                   const int* __restrict__ psrc,
                                                   const float* __restrict__ a_s,
                                                   const float* __restrict__ a_d,
                                                   float* __restrict__ alpha_p) {
    const int wv = threadIdx.x >> 6, lane = threadIdx.x & 63;
    const int n = blockIdx.x * 4 + wv;
    if (n >= NN) return;
    const int h = lane & 3, jl = lane >> 2;
    const int r0 = rowptr[n], r1 = rowptr[n + 1];
    if (r0 == r1) return;   // empty segment: nothing referenced downstream
    const float ad = a_d[n * NH + h];

    float m = -1e30f, s = 0.f;
    for (int j0 = r0; j0 < r1; j0 += 16) {
        const int j = j0 + jl;
        if (j < r1) {
            const int sn = psrc[j];
            float a = a_s[sn * NH + h] + ad;
            a = (a > 0.f) ? a : 0.2f * a;
            alpha_p[j * NH + h] = a;          // stash score
            const float mn = fmaxf(m, a);
            s = s * expf(m - mn) + expf(a - mn);
            m = mn;
        }
    }
    #pragma unroll
    for (int msk = 4; msk < 64; msk <<= 1) {
        const float mo = __shfl_xor(m, msk, 64);
        const float so = __shfl_xor(s, msk, 64);
        const float mn = fmaxf(m, mo);
        s = s * expf(m - mn) + so * expf(mo - mn);
        m = mn;
    }
    const float inv = 1.f / (s + 1e-16f);

    for (int j0 = r0; j0 < r1; j0 += 16) {
        const int j = j0 + jl;
        if (j < r1) {
            const float a = alpha_p[j * NH + h];
            alpha_p[j * NH + h] = expf(a - m) * inv;
        }
    }
}

// ---------- wave-per-node CSR aggregate + head-mean + bias, HC=256 (L1) ----------
// Unroll 8: 8 KB of gathers in flight per wave.
__global__ __launch_bounds__(256) void aggregate_w256(const int* __restrict__ rowptr,
                                                      const int* __restrict__ psrc,
                                                      const float* __restrict__ alpha_p,
                                                      const float* __restrict__ xl,
                                                      const float* __restrict__ bias,
                                                      float* __restrict__ out) {
    const int wv = threadIdx.x >> 6, lane = threadIdx.x & 63;
    const int n = blockIdx.x * 4 + wv;
    if (n >= NN) return;
    const int hh = lane >> 4;
    const int r0 = rowptr[n], r1 = rowptr[n + 1];
    const float4* X4 = (const float4*)xl;   // row stride 64 float4

    float4 A0 = {0,0,0,0}, A1 = {0,0,0,0}, A2 = {0,0,0,0}, A3 = {0,0,0,0};
    int j = r0;
    for (; j + 7 < r1; j += 8) {
        int s[8]; float w[8]; float4 v[8];
        #pragma unroll
        for (int q = 0; q < 8; ++q) {
            s[q] = psrc[j + q];
            w[q] = alpha_p[(j + q) * NH + hh];
        }
        #pragma unroll
        for (int q = 0; q < 8; ++q) v[q] = X4[(size_t)s[q] * 64 + lane];
        #pragma unroll
        for (int q = 0; q < 8; ++q) {
            float4& A = (q & 3) == 0 ? A0 : (q & 3) == 1 ? A1 : (q & 3) == 2 ? A2 : A3;
            A.x = fmaf(w[q], v[q].x, A.x); A.y = fmaf(w[q], v[q].y, A.y);
            A.z = fmaf(w[q], v[q].z, A.z); A.w = fmaf(w[q], v[q].w, A.w);
        }
    }
    for (; j + 3 < r1; j += 4) {
        int s[4]; float w[4]; float4 v[4];
        #pragma unroll
        for (int q = 0; q < 4; ++q) {
            s[q] = psrc[j + q];
            w[q] = alpha_p[(j + q) * NH + hh];
        }
        #pragma unroll
        for (int q = 0; q < 4; ++q) v[q] = X4[(size_t)s[q] * 64 + lane];
        A0.x = fmaf(w[0], v[0].x, A0.x); A0.y = fmaf(w[0], v[0].y, A0.y);
        A0.z = fmaf(w[0], v[0].z, A0.z); A0.w = fmaf(w[0], v[0].w, A0.w);
        A1.x = fmaf(w[1], v[1].x, A1.x); A1.y = fmaf(w[1], v[1].y, A1.y);
        A1.z = fmaf(w[1], v[1].z, A1.z); A1.w = fmaf(w[1], v[1].w, A1.w);
        A2.x = fmaf(w[2], v[2].x, A2.x); A2.y = fmaf(w[2], v[2].y, A2.y);
        A2.z = fmaf(w[2], v[2].z, A2.z); A2.w = fmaf(w[2], v[2].w, A2.w);
        A3.x = fmaf(w[3], v[3].x, A3.x); A3.y = fmaf(w[3], v[3].y, A3.y);
        A3.z = fmaf(w[3], v[3].z, A3.z); A3.w = fmaf(w[3], v[3].w, A3.w);
    }
    for (; j < r1; ++j) {
        const int s0 = psrc[j];
        const float w0 = alpha_p[j*NH + hh];
        const float4 v0 = X4[(size_t)s0*64 + lane];
        A0.x = fmaf(w0, v0.x, A0.x); A0.y = fmaf(w0, v0.y, A0.y);
        A0.z = fmaf(w0, v0.z, A0.z); A0.w = fmaf(w0, v0.w, A0.w);
    }
    float4 t;
    t.x = (A0.x + A1.x) + (A2.x + A3.x);
    t.y = (A0.y + A1.y) + (A2.y + A3.y);
    t.z = (A0.z + A1.z) + (A2.z + A3.z);
    t.w = (A0.w + A1.w) + (A2.w + A3.w);
    #pragma unroll
    for (int msk = 16; msk < 64; msk <<= 1) {
        t.x += __shfl_xor(t.x, msk, 64);
        t.y += __shfl_xor(t.y, msk, 64);
        t.z += __shfl_xor(t.z, msk, 64);
        t.w += __shfl_xor(t.w, msk, 64);
    }
    if (lane < 16) {
        const float4 b = ((const float4*)bias)[lane];
        float4 o;
        o.x = t.x * 0.25f + b.x; o.y = t.y * 0.25f + b.y;
        o.z = t.z * 0.25f + b.z; o.w = t.w * 0.25f + b.w;
        ((float4*)out)[(size_t)n * 16 + lane] = o;
    }
}

// ---------- wave-per-node CSR aggregate, HC=128 (L2): half-wave per edge ----------
// Unroll: 8 edges per iter (4 per half-wave).
__global__ __launch_bounds__(256) void aggregate_w128(const int* __restrict__ rowptr,
                                                      const int* __restrict__ psrc,
                                                      const float* __restrict__ alpha_p,
                                                      const float* __restrict__ xl,
                                                      const float* __restrict__ bias,
                                                      float* __restrict__ out) {
    const int wv = threadIdx.x >> 6, lane = threadIdx.x & 63;
    const int n = blockIdx.x * 4 + wv;
    if (n >= NN) return;
    const int cl = lane & 31, half = lane >> 5;
    const int hh = cl >> 3;                 // head = (cl*4)/32
    const int r0 = rowptr[n], r1 = rowptr[n + 1];
    const float4* X4 = (const float4*)xl;   // row stride 32 float4

    float4 A0 = {0,0,0,0}, A1 = {0,0,0,0}, A2 = {0,0,0,0}, A3 = {0,0,0,0};
    int jb = r0;
    for (; jb + 7 < r1; jb += 8) {
        int s[4]; float w[4]; float4 v[4];
        #pragma unroll
        for (int q = 0; q < 4; ++q) {
            const int ja = jb + 2 * q + half;
            s[q] = psrc[ja];
            w[q] = alpha_p[ja * NH + hh];
        }
        #pragma unroll
        for (int q = 0; q < 4; ++q) v[q] = X4[(size_t)s[q] * 32 + cl];
        A0.x = fmaf(w[0], v[0].x, A0.x); A0.y = fmaf(w[0], v[0].y, A0.y);
        A0.z = fmaf(w[0], v[0].z, A0.z); A0.w = fmaf(w[0], v[0].w, A0.w);
        A1.x = fmaf(w[1], v[1].x, A1.x); A1.y = fmaf(w[1], v[1].y, A1.y);
        A1.z = fmaf(w[1], v[1].z, A1.z); A1.w = fmaf(w[1], v[1].w, A1.w);
        A2.x = fmaf(w[2], v[2].x, A2.x); A2.y = fmaf(w[2], v[2].y, A2.y);
        A2.z = fmaf(w[2], v[2].z, A2.z); A2.w = fmaf(w[2], v[2].w, A2.w);
        A3.x = fmaf(w[3], v[3].x, A3.x); A3.y = fmaf(w[3], v[3].y, A3.y);
        A3.z = fmaf(w[3], v[3].z, A3.z); A3.w = fmaf(w[3], v[3].w, A3.w);
    }
    for (; jb < r1; jb += 2) {
        const int ja = jb + half;
        const bool valid = ja < r1;
        const int sa = psrc[valid ? ja : r0];
        const float wa = valid ? alpha_p[ja*NH + hh] : 0.f;
        const float4 va = X4[(size_t)sa*32 + cl];
        A0.x = fmaf(wa, va.x, A0.x); A0.y = fmaf(wa, va.y, A0.y);
        A0.z = fmaf(wa, va.z, A0.z); A0.w = fmaf(wa, va.w, A0.w);
    }
    float4 t;
    t.x = (A0.x + A1.x) + (A2.x + A3.x);
    t.y = (A0.y + A1.y) + (A2.y + A3.y);
    t.z = (A0.z + A1.z) + (A2.z + A3.z);
    t.w = (A0.w + A1.w) + (A2.w + A3.w);
    #pragma unroll
    for (int q = 0; q < 3; ++q) {
        const int msk = (q == 0) ? 32 : (q == 1) ? 8 : 16;
        t.x += __shfl_xor(t.x, msk, 64);
        t.y += __shfl_xor(t.y, msk, 64);
        t.z += __shfl_xor(t.z, msk, 64);
        t.w += __shfl_xor(t.w, msk, 64);
    }
    if (lane < 8) {
        const float4 b = ((const float4*)bias)[lane];
        float4 o;
        o.x = t.x * 0.25f + b.x; o.y = t.y * 0.25f + b.y;
        o.z = t.z * 0.25f + b.z; o.w = t.w * 0.25f + b.w;
        ((float4*)out)[(size_t)n * 8 + lane] = o;
    }
}

// ---------- pack W1 src/dst row-blocks into [32][128] for the PQ GEMM ----------
__global__ __launch_bounds__(256) void pack_w1(const float* __restrict__ mW1,
                                               float* __restrict__ W1pq) {
    const int idx = blockIdx.x * 256 + threadIdx.x;   // 32*128 = 4096
    if (idx >= 32 * 128) return;
    const int k = idx >> 7, j = idx & 127;
    W1pq[idx] = (j < 64) ? mW1[k * 64 + j] : mW1[(36 + k) * 64 + (j - 64)];
}

// ---------- factored edge MLP v2: 4 edges per wave, 16 lanes (x float4 hid) per edge ----
__global__ __launch_bounds__(256) void edge_mlp_fast2(const float* __restrict__ PQ,      // [N,128]
                                                      const float* __restrict__ alpha_p, // [E,4] CSR
                                                      const int* __restrict__ psrc,
                                                      const int* __restrict__ pdst,
                                                      const int* __restrict__ perm,
                                                      const float* __restrict__ mW1,     // rows 32..35
                                                      const float* __restrict__ mb1,
                                                      const float* __restrict__ mW2,
                                                      const float* __restrict__ mb2,
                                                      float* __restrict__ out) {         // [E,2]
    const int lane = threadIdx.x & 63, wv = threadIdx.x >> 6;
    const int g = lane >> 4, c = lane & 15;

    const float4 wa0 = *(const float4*)&mW1[32 * 64 + c * 4];
    const float4 wa1 = *(const float4*)&mW1[33 * 64 + c * 4];
    const float4 wa2 = *(const float4*)&mW1[34 * 64 + c * 4];
    const float4 wa3 = *(const float4*)&mW1[35 * 64 + c * 4];
    const float4 b1v = *(const float4*)&mb1[c * 4];
    const float4 w2a = *(const float4*)&mW2[c * 8];
    const float4 w2b = *(const float4*)&mW2[c * 8 + 4];
    const float bo0 = mb2[0], bo1 = mb2[1];

    const float4* PQ4 = (const float4*)PQ;   // row stride 32 float4
    const int gw = blockIdx.x * 4 + wv;
    const int stride4 = gridDim.x * 4 * 4;

    for (int jb = gw * 4; jb < EE; jb += stride4) {
        const int j = jb + g;
        const int s = psrc[j];
        const int d = pdst[j];
        const float4 al = *(const float4*)&alpha_p[(size_t)j * 4];
        const float4 p = PQ4[(size_t)s * 32 + c];
        const float4 q = PQ4[(size_t)d * 32 + 16 + c];
        float4 h;
        h.x = p.x + q.x + b1v.x; h.y = p.y + q.y + b1v.y;
        h.z = p.z + q.z + b1v.z; h.w = p.w + q.w + b1v.w;
        h.x = fmaf(al.x, wa0.x, h.x); h.y = fmaf(al.x, wa0.y, h.y);
        h.z = fmaf(al.x, wa0.z, h.z); h.w = fmaf(al.x, wa0.w, h.w);
        h.x = fmaf(al.y, wa1.x, h.x); h.y = fmaf(al.y, wa1.y, h.y);
        h.z = fmaf(al.y, wa1.z, h.z); h.w = fmaf(al.y, wa1.w, h.w);
        h.x = fmaf(al.z, wa2.x, h.x); h.y = fmaf(al.z, wa2.y, h.y);
        h.z = fmaf(al.z, wa2.z, h.z); h.w = fmaf(al.z, wa2.w, h.w);
        h.x = fmaf(al.w, wa3.x, h.x); h.y = fmaf(al.w, wa3.y, h.y);
        h.z = fmaf(al.w, wa3.z, h.z); h.w = fmaf(al.w, wa3.w, h.w);
        h.x = fmaxf(h.x, 0.f); h.y = fmaxf(h.y, 0.f);
        h.z = fmaxf(h.z, 0.f); h.w = fmaxf(h.w, 0.f);

        float v0 = h.x * w2a.x + h.y * w2a.z + h.z * w2b.x + h.w * w2b.z;
        float v1 = h.x * w2a.y + h.y * w2a.w + h.z * w2b.y + h.w * w2b.w;
        #pragma unroll
        for (int msk = 1; msk < 16; msk <<= 1) {
            v0 += __shfl_xor(v0, msk, 64);
            v1 += __shfl_xor(v1, msk, 64);
        }
        if (c == 0)
            *(float2*)&out[(size_t)perm[j] * 2] = make_float2(v0 + bo0, v1 + bo1);
    }
}

extern "C" void kernel_launch(void* const* d_in, const int* in_sizes, int n_in,
                              void* d_out, int out_size, void* d_ws, size_t ws_size,
                              hipStream_t stream) {
    const float* x        = (const float*)d_in[0];
    const int*   ei       = (const int*)d_in[1];
    // d_in[2] edge_attr: unused (edge_dim=None). d_in[3] flag: unused.
    const float* W1       = (const float*)d_in[4];
    const float* att1_src = (const float*)d_in[5];
    const float* att1_dst = (const float*)d_in[6];
    const float* b1       = (const float*)d_in[7];
    const float* W3       = (const float*)d_in[8];
    const float* att3_src = (const float*)d_in[9];
    const float* att3_dst = (const float*)d_in[10];
    const float* b3       = (const float*)d_in[11];
    const float* mW1      = (const float*)d_in[12];
    const float* mb1      = (const float*)d_in[13];
    const float* mW2      = (const float*)d_in[14];
    const float* mb2      = (const float*)d_in[15];

    float* out_nodes = (float*)d_out;               // [N,32]
    float* out_edges = out_nodes + (size_t)NN * 32; // [E,2]

    // workspace layout (floats/ints)
    float* ws = (float*)d_ws;
    float*    xl      = ws;                           // N*256 = 12.8M (layer GEMM out)
    float*    PQ      = ws;                           // N*128, written AFTER xl's last use
    float*    h1      = ws + 12800000;                // N*64
    float*    alpha_p = ws + 16000000;                // E*4 (CSR-order scores->alpha_n)
    float*    a_s     = ws + 25600000;                // N*4
    float*    a_d     = ws + 25800000;                // N*4
    float*    W1pq    = ws + 26000000;                // 32*128
    int*      deg     = (int*)(ws + 26400000);        // N
    int*      cursor  = (int*)(ws + 26450000);        // N
    int*      rowptr  = (int*)(ws + 26500000);        // N+1
    int*      perm    = (int*)(ws + 26550008);        // E
    int*      psrc    = (int*)(ws + 27350008);        // E
    int*      pdst    = (int*)(ws + 28150008);        // E

    const int gemmRows64  = (NN + 63) / 64;    // 782 (PQ GEMM)
    const int gemmRows128 = (NN + 127) / 128;  // 391
    const int EB = (EE + 255) / 256;           // 3125
    const int NB4 = (NN + 3) / 4;              // wave-per-node blocks (4 waves/block)

    // ======== CSR build (shared by both layers) ========
    hipMemsetAsync(deg, 0, (size_t)NN * 4, stream);
    count_deg_k<<<EB, 256, 0, stream>>>(ei, deg);
    scan_k<<<1, 1024, 0, stream>>>(deg, rowptr, cursor);
    scatter_perm_k<<<EB, 256, 0, stream>>>(ei, cursor, perm, psrc, pdst);
    pack_w1<<<16, 256, 0, stream>>>(mW1, W1pq);

    // ======== Layer 1 (C=64, HC=256) ========
    gemm_att128<64><<<dim3(gemmRows128, 2), 256, 0, stream>>>(x, W1, xl, att1_src, att1_dst,
                                                              a_s, a_d, NN, INF, NH * 64);
    softmax_csr<<<NB4, 256, 0, stream>>>(rowptr, psrc, a_s, a_d, alpha_p);
    aggregate_w256<<<NB4, 256, 0, stream>>>(rowptr, psrc, alpha_p, xl, b1, h1);

    // ======== Layer 2 (C=32, HC=128) ========
    gemm_att128<32><<<dim3(gemmRows128, 1), 256, 0, stream>>>(h1, W3, xl, att3_src, att3_dst,
                                                              a_s, a_d, NN, 64, NH * 32);
    softmax_csr<<<NB4, 256, 0, stream>>>(rowptr, psrc, a_s, a_d, alpha_p);
    aggregate_w128<<<NB4, 256, 0, stream>>>(rowptr, psrc, alpha_p, xl, b3, out_nodes);

    // ======== Edge MLP (factored): PQ = out_nodes @ [W1[0:32] | W1[36:68]] ========
    // xl is dead after aggregate_w128 -> reuse its region for PQ.
    gemm_tiled<<<dim3(gemmRows64, 2), 256, 0, stream>>>(out_nodes, W1pq, PQ, NN, 32, 128);
    edge_mlp_fast2<<<2048, 256, 0, stream>>>(PQ, alpha_p, psrc, pdst, perm,
                                             mW1, mb1, mW2, mb2, out_edges);
}

// Round 9
// 558.177 us; speedup vs baseline: 1.0938x; 1.0938x over previous
//
#include <hip/hip_runtime.h>

// Problem constants
constexpr int NN   = 50000;
constexpr int EE   = 800000;
constexpr int INF  = 128;   // input feat
constexpr int NH   = 4;     // heads

// ---------- Tiled fp32 GEMM (64x64, 4x4): used for the small PQ GEMM ----------
__global__ __launch_bounds__(256) void gemm_tiled(const float* __restrict__ A,
                                                  const float* __restrict__ B,
                                                  float* __restrict__ C,
                                                  int N, int K, int M) {
    __shared__ float As[16][68];   // [k][row], padded
    __shared__ float Bs[16][64];   // [k][col]
    const int tid = threadIdx.x;
    const int tx = tid & 15, ty = tid >> 4;
    const int row0 = blockIdx.x * 64, col0 = blockIdx.y * 64;

    float acc[4][4] = {};

    for (int k0 = 0; k0 < K; k0 += 16) {
        {
            const int a_row = tid >> 2;
            const int a_k   = (tid & 3) * 4;
            const int gr    = row0 + a_row;
            float4 v = make_float4(0.f, 0.f, 0.f, 0.f);
            if (gr < N) v = *(const float4*)(A + (size_t)gr * K + k0 + a_k);
            As[a_k + 0][a_row] = v.x;
            As[a_k + 1][a_row] = v.y;
            As[a_k + 2][a_row] = v.z;
            As[a_k + 3][a_row] = v.w;
        }
        {
            const int b_k = tid >> 4;
            const int b_c = (tid & 15) * 4;
            float4 w = *(const float4*)(B + (size_t)(k0 + b_k) * M + col0 + b_c);
            *(float4*)&Bs[b_k][b_c] = w;
        }
        __syncthreads();
        #pragma unroll
        for (int kk = 0; kk < 16; ++kk) {
            float4 a = *(const float4*)&As[kk][ty * 4];
            float4 b = *(const float4*)&Bs[kk][tx * 4];
            const float av[4] = {a.x, a.y, a.z, a.w};
            const float bv[4] = {b.x, b.y, b.z, b.w};
            #pragma unroll
            for (int i = 0; i < 4; ++i)
                #pragma unroll
                for (int j = 0; j < 4; ++j)
                    acc[i][j] = fmaf(av[i], bv[j], acc[i][j]);
        }
        __syncthreads();
    }
    #pragma unroll
    for (int i = 0; i < 4; ++i) {
        const int r = row0 + ty * 4 + i;
        if (r < N) {
            float* cp = C + (size_t)r * M + col0 + tx * 4;
            cp[0] = acc[i][0]; cp[1] = acc[i][1]; cp[2] = acc[i][2]; cp[3] = acc[i][3];
        }
    }
}

// ---------- Tiled fp32 GEMM (64-tile) with fused attention-score epilogue ----------
template <int CH>
__global__ __launch_bounds__(256) void gemm_att(const float* __restrict__ A,
                                                const float* __restrict__ B,
                                                float* __restrict__ C,
                                                const float* __restrict__ att_s,
                                                const float* __restrict__ att_d,
                                                float* __restrict__ a_s,
                                                float* __restrict__ a_d,
                                                int N, int K, int M) {
    __shared__ float As[16][68];   // [k][row], padded
    __shared__ float Bs[16][64];   // [k][col]
    const int tid = threadIdx.x;
    const int tx = tid & 15, ty = tid >> 4;
    const int row0 = blockIdx.x * 64, col0 = blockIdx.y * 64;

    const int col  = col0 + tx * 4;
    const int head = col / CH;
    const int pos  = col % CH;
    float attS[4], attD[4];
    #pragma unroll
    for (int j = 0; j < 4; ++j) {
        attS[j] = att_s[head * CH + pos + j];
        attD[j] = att_d[head * CH + pos + j];
    }

    float acc[4][4] = {};

    for (int k0 = 0; k0 < K; k0 += 16) {
        {
            const int a_row = tid >> 2;
            const int a_k   = (tid & 3) * 4;
            const int gr    = row0 + a_row;
            float4 v = make_float4(0.f, 0.f, 0.f, 0.f);
            if (gr < N) v = *(const float4*)(A + (size_t)gr * K + k0 + a_k);
            As[a_k + 0][a_row] = v.x;
            As[a_k + 1][a_row] = v.y;
            As[a_k + 2][a_row] = v.z;
            As[a_k + 3][a_row] = v.w;
        }
        {
            const int b_k = tid >> 4;
            const int b_c = (tid & 15) * 4;
            float4 w = *(const float4*)(B + (size_t)(k0 + b_k) * M + col0 + b_c);
            *(float4*)&Bs[b_k][b_c] = w;
        }
        __syncthreads();
        #pragma unroll
        for (int kk = 0; kk < 16; ++kk) {
            float4 a = *(const float4*)&As[kk][ty * 4];
            float4 b = *(const float4*)&Bs[kk][tx * 4];
            const float av[4] = {a.x, a.y, a.z, a.w};
            const float bv[4] = {b.x, b.y, b.z, b.w};
            #pragma unroll
            for (int i = 0; i < 4; ++i)
                #pragma unroll
                for (int j = 0; j < 4; ++j)
                    acc[i][j] = fmaf(av[i], bv[j], acc[i][j]);
        }
        __syncthreads();
    }
    #pragma unroll
    for (int i = 0; i < 4; ++i) {
        const int r = row0 + ty * 4 + i;
        if (r < N) {
            float* cp = C + (size_t)r * M + col0 + tx * 4;
            cp[0] = acc[i][0]; cp[1] = acc[i][1]; cp[2] = acc[i][2]; cp[3] = acc[i][3];
        }
        float ss = 0.f, sd = 0.f;
        #pragma unroll
        for (int j = 0; j < 4; ++j) {
            ss = fmaf(acc[i][j], attS[j], ss);
            sd = fmaf(acc[i][j], attD[j], sd);
        }
        #pragma unroll
        for (int msk = 1; msk < CH / 4; msk <<= 1) {
            ss += __shfl_xor(ss, msk, 64);
            sd += __shfl_xor(sd, msk, 64);
        }
        if ((tx & (CH / 4 - 1)) == 0 && r < N) {
            a_s[r * NH + head] = ss;
            a_d[r * NH + head] = sd;
        }
    }
}

// ---------- CSR build ----------
__global__ __launch_bounds__(256) void count_deg_k(const int* __restrict__ ei,
                                                   int* __restrict__ deg) {
    const int e = blockIdx.x * 256 + threadIdx.x;
    if (e < EE) atomicAdd(&deg[ei[EE + e]], 1);
}

// single-block exclusive scan over deg[0..NN) -> rowptr[0..NN], cursor copy
__global__ __launch_bounds__(1024) void scan_k(const int* __restrict__ deg,
                                               int* __restrict__ rowptr,
                                               int* __restrict__ cursor) {
    __shared__ int wsum[16];
    const int tid = threadIdx.x;
    const int lane = tid & 63, wv = tid >> 6;
    int total = 0;
    for (int base = 0; base < NN; base += 1024) {
        const int i = base + tid;
        const int v = (i < NN) ? deg[i] : 0;
        int incl = v;
        #pragma unroll
        for (int d = 1; d < 64; d <<= 1) {
            int t = __shfl_up(incl, d, 64);
            if (lane >= d) incl += t;
        }
        if (lane == 63) wsum[wv] = incl;
        __syncthreads();
        if (wv == 0) {
            int s = (lane < 16) ? wsum[lane] : 0;
            #pragma unroll
            for (int d = 1; d < 16; d <<= 1) {
                int t = __shfl_up(s, d, 64);
                if (lane >= d) s += t;
            }
            if (lane < 16) wsum[lane] = s;
        }
        __syncthreads();
        const int excl = total + (wv > 0 ? wsum[wv - 1] : 0) + incl - v;
        const int chunk = wsum[15];
        if (i < NN) { rowptr[i] = excl; cursor[i] = excl; }
        total += chunk;
        __syncthreads();   // protect wsum before next iteration's writes
    }
    if (tid == 0) rowptr[NN] = total;
}

__global__ __launch_bounds__(256) void scatter_perm_k(const int* __restrict__ ei,
                                                      int* __restrict__ cursor,
                                                      int* __restrict__ perm,
                                                      int* __restrict__ psrc,
                                                      int* __restrict__ pdst) {
    const int e = blockIdx.x * 256 + threadIdx.x;
    if (e >= EE) return;
    const int d = ei[EE + e];
    const int p = atomicAdd(&cursor[d], 1);
    perm[p] = e;
    psrc[p] = ei[e];
    pdst[p] = d;
}

// ---------- fused softmax + aggregate, HC=256 (L1). One wave per dst node. ----------
// Phase 1 (lane=(jl,h)): scores -> alpha_p stash, online m/s, xor-merge.
// Phase 2 (lane=channel-quad, hh=lane>>4): w = exp(a - m_h)*inv_h on the fly,
// gather-FMA, head-mean via shfl, + bias, store. L1 writes no normalized alpha.
__global__ __launch_bounds__(256) void softagg_w256(const int* __restrict__ rowptr,
                                                    const int* __restrict__ psrc,
                                                    const float* __restrict__ a_s,
                                                    const float* __restrict__ a_d,
                                                    float* __restrict__ alpha_p,
                                                    const float* __restrict__ xl,
                                                    const float* __restrict__ bias,
                                                    float* __restrict__ out) {
    const int wv = threadIdx.x >> 6, lane = threadIdx.x & 63;
    const int n = blockIdx.x * 4 + wv;
    if (n >= NN) return;
    const int r0 = rowptr[n], r1 = rowptr[n + 1];

    // ---- phase 1: softmax stats ----
    const int h = lane & 3, jl = lane >> 2;
    float m = -1e30f, s = 0.f;
    if (r0 < r1) {
        const float ad = a_d[n * NH + h];
        for (int j0 = r0; j0 < r1; j0 += 16) {
            const int j = j0 + jl;
            if (j < r1) {
                const int sn = psrc[j];
                float a = a_s[sn * NH + h] + ad;
                a = (a > 0.f) ? a : 0.2f * a;
                alpha_p[j * NH + h] = a;          // stash raw score
                const float mn = fmaxf(m, a);
                s = s * expf(m - mn) + expf(a - mn);
                m = mn;
            }
        }
        #pragma unroll
        for (int msk = 4; msk < 64; msk <<= 1) {
            const float mo = __shfl_xor(m, msk, 64);
            const float so = __shfl_xor(s, msk, 64);
            const float mn = fmaxf(m, mo);
            s = s * expf(m - mn) + so * expf(mo - mn);
            m = mn;
        }
    }
    const float inv = 1.f / (s + 1e-16f);

    // ---- redistribute per-head stats to channel mapping ----
    const int hh = lane >> 4;
    const float mh   = __shfl(m, hh, 64);     // lane hh holds head hh's stats
    const float invh = __shfl(inv, hh, 64);

    // ---- phase 2: weighted gather-aggregate ----
    const float4* X4 = (const float4*)xl;   // row stride 64 float4
    float4 A0 = {0,0,0,0}, A1 = {0,0,0,0}, A2 = {0,0,0,0}, A3 = {0,0,0,0};
    int j = r0;
    for (; j + 3 < r1; j += 4) {
        const int s0 = psrc[j], s1 = psrc[j+1], s2 = psrc[j+2], s3 = psrc[j+3];
        const float w0 = expf(alpha_p[j*NH + hh]     - mh) * invh;
        const float w1 = expf(alpha_p[(j+1)*NH + hh] - mh) * invh;
        const float w2 = expf(alpha_p[(j+2)*NH + hh] - mh) * invh;
        const float w3 = expf(alpha_p[(j+3)*NH + hh] - mh) * invh;
        const float4 v0 = X4[(size_t)s0*64 + lane];
        const float4 v1 = X4[(size_t)s1*64 + lane];
        const float4 v2 = X4[(size_t)s2*64 + lane];
        const float4 v3 = X4[(size_t)s3*64 + lane];
        A0.x = fmaf(w0, v0.x, A0.x); A0.y = fmaf(w0, v0.y, A0.y);
        A0.z = fmaf(w0, v0.z, A0.z); A0.w = fmaf(w0, v0.w, A0.w);
        A1.x = fmaf(w1, v1.x, A1.x); A1.y = fmaf(w1, v1.y, A1.y);
        A1.z = fmaf(w1, v1.z, A1.z); A1.w = fmaf(w1, v1.w, A1.w);
        A2.x = fmaf(w2, v2.x, A2.x); A2.y = fmaf(w2, v2.y, A2.y);
        A2.z = fmaf(w2, v2.z, A2.z); A2.w = fmaf(w2, v2.w, A2.w);
        A3.x = fmaf(w3, v3.x, A3.x); A3.y = fmaf(w3, v3.y, A3.y);
        A3.z = fmaf(w3, v3.z, A3.z); A3.w = fmaf(w3, v3.w, A3.w);
    }
    for (; j < r1; ++j) {
        const int s0 = psrc[j];
        const float w0 = expf(alpha_p[j*NH + hh] - mh) * invh;
        const float4 v0 = X4[(size_t)s0*64 + lane];
        A0.x = fmaf(w0, v0.x, A0.x); A0.y = fmaf(w0, v0.y, A0.y);
        A0.z = fmaf(w0, v0.z, A0.z); A0.w = fmaf(w0, v0.w, A0.w);
    }
    float4 t;
    t.x = (A0.x + A1.x) + (A2.x + A3.x);
    t.y = (A0.y + A1.y) + (A2.y + A3.y);
    t.z = (A0.z + A1.z) + (A2.z + A3.z);
    t.w = (A0.w + A1.w) + (A2.w + A3.w);
    #pragma unroll
    for (int msk = 16; msk < 64; msk <<= 1) {
        t.x += __shfl_xor(t.x, msk, 64);
        t.y += __shfl_xor(t.y, msk, 64);
        t.z += __shfl_xor(t.z, msk, 64);
        t.w += __shfl_xor(t.w, msk, 64);
    }
    if (lane < 16) {
        const float4 b = ((const float4*)bias)[lane];
        float4 o;
        o.x = t.x * 0.25f + b.x; o.y = t.y * 0.25f + b.y;
        o.z = t.z * 0.25f + b.z; o.w = t.w * 0.25f + b.w;
        ((float4*)out)[(size_t)n * 16 + lane] = o;
    }
}

// ---------- fused softmax + aggregate, HC=128 (L2): half-wave per edge ----------
// Also overwrites alpha_p with the NORMALIZED alpha (needed by edge_mlp_fast2).
__global__ __launch_bounds__(256) void softagg_w128(const int* __restrict__ rowptr,
                                                    const int* __restrict__ psrc,
                                                    const float* __restrict__ a_s,
                                                    const float* __restrict__ a_d,
                                                    float* __restrict__ alpha_p,
                                                    const float* __restrict__ xl,
                                                    const float* __restrict__ bias,
                                                    float* __restrict__ out) {
    const int wv = threadIdx.x >> 6, lane = threadIdx.x & 63;
    const int n = blockIdx.x * 4 + wv;
    if (n >= NN) return;
    const int r0 = rowptr[n], r1 = rowptr[n + 1];

    // ---- phase 1: softmax stats (lane = (jl,h)) ----
    const int h = lane & 3, jl = lane >> 2;
    float m = -1e30f, s = 0.f;
    if (r0 < r1) {
        const float ad = a_d[n * NH + h];
        for (int j0 = r0; j0 < r1; j0 += 16) {
            const int j = j0 + jl;
            if (j < r1) {
                const int sn = psrc[j];
                float a = a_s[sn * NH + h] + ad;
                a = (a > 0.f) ? a : 0.2f * a;
                alpha_p[j * NH + h] = a;
                const float mn = fmaxf(m, a);
                s = s * expf(m - mn) + expf(a - mn);
                m = mn;
            }
        }
        #pragma unroll
        for (int msk = 4; msk < 64; msk <<= 1) {
            const float mo = __shfl_xor(m, msk, 64);
            const float so = __shfl_xor(s, msk, 64);
            const float mn = fmaxf(m, mo);
            s = s * expf(m - mn) + so * expf(mo - mn);
            m = mn;
        }
    }
    const float inv = 1.f / (s + 1e-16f);

    // ---- redistribute: cl = lane&31 channel-quad, half = lane>>5, hh = cl>>3 ----
    const int cl = lane & 31, half = lane >> 5;
    const int hh = cl >> 3;
    const float mh   = __shfl(m, hh, 64);
    const float invh = __shfl(inv, hh, 64);
    const bool writer = (cl & 7) == 0;   // one lane per (half, head) writes normalized alpha

    const float4* X4 = (const float4*)xl;   // row stride 32 float4
    float4 A0 = {0,0,0,0}, A1 = {0,0,0,0};
    int jb = r0;
    for (; jb + 3 < r1; jb += 4) {
        const int ja = jb + half, jc = jb + 2 + half;
        const int sa = psrc[ja], sc = psrc[jc];
        const float wa = expf(alpha_p[ja*NH + hh] - mh) * invh;
        const float wc = expf(alpha_p[jc*NH + hh] - mh) * invh;
        if (writer) { alpha_p[ja*NH + hh] = wa; alpha_p[jc*NH + hh] = wc; }
        const float4 va = X4[(size_t)sa*32 + cl];
        const float4 vc = X4[(size_t)sc*32 + cl];
        A0.x = fmaf(wa, va.x, A0.x); A0.y = fmaf(wa, va.y, A0.y);
        A0.z = fmaf(wa, va.z, A0.z); A0.w = fmaf(wa, va.w, A0.w);
        A1.x = fmaf(wc, vc.x, A1.x); A1.y = fmaf(wc, vc.y, A1.y);
        A1.z = fmaf(wc, vc.z, A1.z); A1.w = fmaf(wc, vc.w, A1.w);
    }
    for (; jb < r1; jb += 2) {
        const int ja = jb + half;
        const bool valid = ja < r1;
        const int sa = psrc[valid ? ja : r0];
        float wa = 0.f;
        if (valid) {
            wa = expf(alpha_p[ja*NH + hh] - mh) * invh;
            if (writer) alpha_p[ja*NH + hh] = wa;
        }
        const float4 va = X4[(size_t)sa*32 + cl];
        A0.x = fmaf(wa, va.x, A0.x); A0.y = fmaf(wa, va.y, A0.y);
        A0.z = fmaf(wa, va.z, A0.z); A0.w = fmaf(wa, va.w, A0.w);
    }
    float4 t;
    t.x = A0.x + A1.x; t.y = A0.y + A1.y; t.z = A0.z + A1.z; t.w = A0.w + A1.w;
    #pragma unroll
    for (int q = 0; q < 3; ++q) {
        const int msk = (q == 0) ? 32 : (q == 1) ? 8 : 16;
        t.x += __shfl_xor(t.x, msk, 64);
        t.y += __shfl_xor(t.y, msk, 64);
        t.z += __shfl_xor(t.z, msk, 64);
        t.w += __shfl_xor(t.w, msk, 64);
    }
    if (lane < 8) {
        const float4 b = ((const float4*)bias)[lane];
        float4 o;
        o.x = t.x * 0.25f + b.x; o.y = t.y * 0.25f + b.y;
        o.z = t.z * 0.25f + b.z; o.w = t.w * 0.25f + b.w;
        ((float4*)out)[(size_t)n * 8 + lane] = o;
    }
}

// ---------- pack W1 src/dst row-blocks into [32][128] for the PQ GEMM ----------
__global__ __launch_bounds__(256) void pack_w1(const float* __restrict__ mW1,
                                               float* __restrict__ W1pq) {
    const int idx = blockIdx.x * 256 + threadIdx.x;   // 32*128 = 4096
    if (idx >= 32 * 128) return;
    const int k = idx >> 7, j = idx & 127;
    W1pq[idx] = (j < 64) ? mW1[k * 64 + j] : mW1[(36 + k) * 64 + (j - 64)];
}

// ---------- factored edge MLP v2: 4 edges per wave, 16 lanes (x float4 hid) per edge ----
__global__ __launch_bounds__(256) void edge_mlp_fast2(const float* __restrict__ PQ,      // [N,128]
                                                      const float* __restrict__ alpha_p, // [E,4] CSR
                                                      const int* __restrict__ psrc,
                                                      const int* __restrict__ pdst,
                                                      const int* __restrict__ perm,
                                                      const float* __restrict__ mW1,     // rows 32..35
                                                      const float* __restrict__ mb1,
                                                      const float* __restrict__ mW2,
                                                      const float* __restrict__ mb2,
                                                      float* __restrict__ out) {         // [E,2]
    const int lane = threadIdx.x & 63, wv = threadIdx.x >> 6;
    const int g = lane >> 4, c = lane & 15;

    const float4 wa0 = *(const float4*)&mW1[32 * 64 + c * 4];
    const float4 wa1 = *(const float4*)&mW1[33 * 64 + c * 4];
    const float4 wa2 = *(const float4*)&mW1[34 * 64 + c * 4];
    const float4 wa3 = *(const float4*)&mW1[35 * 64 + c * 4];
    const float4 b1v = *(const float4*)&mb1[c * 4];
    const float4 w2a = *(const float4*)&mW2[c * 8];
    const float4 w2b = *(const float4*)&mW2[c * 8 + 4];
    const float bo0 = mb2[0], bo1 = mb2[1];

    const float4* PQ4 = (const float4*)PQ;   // row stride 32 float4
    const int gw = blockIdx.x * 4 + wv;
    const int stride4 = gridDim.x * 4 * 4;

    for (int jb = gw * 4; jb < EE; jb += stride4) {
        const int j = jb + g;
        const int s = psrc[j];
        const int d = pdst[j];
        const float4 al = *(const float4*)&alpha_p[(size_t)j * 4];
        const float4 p = PQ4[(size_t)s * 32 + c];
        const float4 q = PQ4[(size_t)d * 32 + 16 + c];
        float4 h;
        h.x = p.x + q.x + b1v.x; h.y = p.y + q.y + b1v.y;
        h.z = p.z + q.z + b1v.z; h.w = p.w + q.w + b1v.w;
        h.x = fmaf(al.x, wa0.x, h.x); h.y = fmaf(al.x, wa0.y, h.y);
        h.z = fmaf(al.x, wa0.z, h.z); h.w = fmaf(al.x, wa0.w, h.w);
        h.x = fmaf(al.y, wa1.x, h.x); h.y = fmaf(al.y, wa1.y, h.y);
        h.z = fmaf(al.y, wa1.z, h.z); h.w = fmaf(al.y, wa1.w, h.w);
        h.x = fmaf(al.z, wa2.x, h.x); h.y = fmaf(al.z, wa2.y, h.y);
        h.z = fmaf(al.z, wa2.z, h.z); h.w = fmaf(al.z, wa2.w, h.w);
        h.x = fmaf(al.w, wa3.x, h.x); h.y = fmaf(al.w, wa3.y, h.y);
        h.z = fmaf(al.w, wa3.z, h.z); h.w = fmaf(al.w, wa3.w, h.w);
        h.x = fmaxf(h.x, 0.f); h.y = fmaxf(h.y, 0.f);
        h.z = fmaxf(h.z, 0.f); h.w = fmaxf(h.w, 0.f);

        float v0 = h.x * w2a.x + h.y * w2a.z + h.z * w2b.x + h.w * w2b.z;
        float v1 = h.x * w2a.y + h.y * w2a.w + h.z * w2b.y + h.w * w2b.w;
        #pragma unroll
        for (int msk = 1; msk < 16; msk <<= 1) {
            v0 += __shfl_xor(v0, msk, 64);
            v1 += __shfl_xor(v1, msk, 64);
        }
        if (c == 0)
            *(float2*)&out[(size_t)perm[j] * 2] = make_float2(v0 + bo0, v1 + bo1);
    }
}

extern "C" void kernel_launch(void* const* d_in, const int* in_sizes, int n_in,
                              void* d_out, int out_size, void* d_ws, size_t ws_size,
                              hipStream_t stream) {
    const float* x        = (const float*)d_in[0];
    const int*   ei       = (const int*)d_in[1];
    // d_in[2] edge_attr: unused (edge_dim=None). d_in[3] flag: unused.
    const float* W1       = (const float*)d_in[4];
    const float* att1_src = (const float*)d_in[5];
    const float* att1_dst = (const float*)d_in[6];
    const float* b1       = (const float*)d_in[7];
    const float* W3       = (const float*)d_in[8];
    const float* att3_src = (const float*)d_in[9];
    const float* att3_dst = (const float*)d_in[10];
    const float* b3       = (const float*)d_in[11];
    const float* mW1      = (const float*)d_in[12];
    const float* mb1      = (const float*)d_in[13];
    const float* mW2      = (const float*)d_in[14];
    const float* mb2      = (const float*)d_in[15];

    float* out_nodes = (float*)d_out;               // [N,32]
    float* out_edges = out_nodes + (size_t)NN * 32; // [E,2]

    // workspace layout (floats/ints)
    float* ws = (float*)d_ws;
    float*    xl      = ws;                           // N*256 = 12.8M (layer GEMM out)
    float*    PQ      = ws;                           // N*128, written AFTER xl's last use
    float*    h1      = ws + 12800000;                // N*64
    float*    alpha_p = ws + 16000000;                // E*4 (CSR-order scores->alpha_n)
    float*    a_s     = ws + 25600000;                // N*4
    float*    a_d     = ws + 25800000;                // N*4
    float*    W1pq    = ws + 26000000;                // 32*128
    int*      deg     = (int*)(ws + 26400000);        // N
    int*      cursor  = (int*)(ws + 26450000);        // N
    int*      rowptr  = (int*)(ws + 26500000);        // N+1
    int*      perm    = (int*)(ws + 26550008);        // E
    int*      psrc    = (int*)(ws + 27350008);        // E
    int*      pdst    = (int*)(ws + 28150008);        // E

    const int gemmRows = (NN + 63) / 64;  // 782
    const int EB = (EE + 255) / 256;      // 3125
    const int NB4 = (NN + 3) / 4;         // wave-per-node blocks (4 waves/block)

    // ======== CSR build (shared by both layers) ========
    hipMemsetAsync(deg, 0, (size_t)NN * 4, stream);
    count_deg_k<<<EB, 256, 0, stream>>>(ei, deg);
    scan_k<<<1, 1024, 0, stream>>>(deg, rowptr, cursor);
    scatter_perm_k<<<EB, 256, 0, stream>>>(ei, cursor, perm, psrc, pdst);
    pack_w1<<<16, 256, 0, stream>>>(mW1, W1pq);

    // ======== Layer 1 (C=64, HC=256) ========
    gemm_att<64><<<dim3(gemmRows, 4), 256, 0, stream>>>(x, W1, xl, att1_src, att1_dst,
                                                        a_s, a_d, NN, INF, NH * 64);
    softagg_w256<<<NB4, 256, 0, stream>>>(rowptr, psrc, a_s, a_d, alpha_p, xl, b1, h1);

    // ======== Layer 2 (C=32, HC=128) ========
    gemm_att<32><<<dim3(gemmRows, 2), 256, 0, stream>>>(h1, W3, xl, att3_src, att3_dst,
                                                        a_s, a_d, NN, 64, NH * 32);
    softagg_w128<<<NB4, 256, 0, stream>>>(rowptr, psrc, a_s, a_d, alpha_p, xl, b3, out_nodes);

    // ======== Edge MLP (factored): PQ = out_nodes @ [W1[0:32] | W1[36:68]] ========
    // xl is dead after softagg_w128 -> reuse its region for PQ.
    gemm_tiled<<<dim3(gemmRows, 2), 256, 0, stream>>>(out_nodes, W1pq, PQ, NN, 32, 128);
    edge_mlp_fast2<<<2048, 256, 0, stream>>>(PQ, alpha_p, psrc, pdst, perm,
                                             mW1, mb1, mW2, mb2, out_edges);
}